// Round 3
// baseline (373.182 us; speedup 1.0000x reference)
//
#include <hip/hip_runtime.h>
#include <math.h>

#define N_NODES 20000
#define N_EDGES 320000
#define N_GRAPH 64
#define IN_DIM  512
#define HID     256
#define F2      512   // HEADS*HID
#define EPS_BN  1e-5f
#define SLOPE   0.2f
#define SCAN_BLOCKS 79   // ceil(20000/256)
#define N_RT    157      // ceil(20000/128) row tiles
#define RT_PAD  20096    // 157*128: padded Fhi rows so tail A-loads are in-bounds

// prep mega-kernel block ranges (init + split_feat + split_wt + hist fused)
#define SF_BLOCKS   5024   // RT_PAD*512/8/256
#define SW_BLOCKS   1024   // 16 x 16 x 4
#define INIT_BLOCKS 79
#define HIST_BLOCKS 1250
#define PREP_BLOCKS (SF_BLOCKS + SW_BLOCKS + INIT_BLOCKS + HIST_BLOCKS)
// triple launch: 1920 GEMM blocks + 79 scan_local rider blocks
#define TRIPLE_BLOCKS 1920

typedef unsigned short u16;
typedef __attribute__((ext_vector_type(8))) short bf16x8;
typedef __attribute__((ext_vector_type(4))) float floatx4;
typedef _Float16 f16;
typedef __attribute__((ext_vector_type(2))) f16 f16x2;

// bf16 helpers: storage = upper 16 bits of fp32, round-to-nearest-even
__device__ __forceinline__ u16 bf_hi(float x) {
    unsigned int u = __float_as_uint(x);
    return (u16)((u + 0x7fffu + ((u >> 16) & 1u)) >> 16);
}
__device__ __forceinline__ float bf_val(u16 h) {
    return __uint_as_float((unsigned int)h << 16);
}
__device__ __forceinline__ f16x2 h2_from_u32(unsigned int u) {
    return __builtin_bit_cast(f16x2, u);
}
__device__ __forceinline__ unsigned int u32_from_h2(f16x2 h) {
    return __builtin_bit_cast(unsigned int, h);
}

// async global->LDS DMA, 16B per lane, dest = uniform base + lane*16
__device__ __forceinline__ void gload16(const u16* g, u16* l) {
    __builtin_amdgcn_global_load_lds(
        (const __attribute__((address_space(1))) void*)g,
        (__attribute__((address_space(3))) void*)l, 16, 0, 0);
}

// ------- prep mega-kernel: split_feat + split_wt + init + hist ----------
__global__ __launch_bounds__(256) void prep_kernel(
    const float* __restrict__ feat, u16* __restrict__ Fhi,
    const float* __restrict__ Ws, const float* __restrict__ Wd,
    const float* __restrict__ Wk, const float* __restrict__ Wr,
    u16* __restrict__ Whi, u16* __restrict__ Wlo,
    const int* __restrict__ dst, int* __restrict__ counts,
    int* __restrict__ cursor,
    float* __restrict__ stats, float* __restrict__ h_gnum,
    float* __restrict__ gden, float* __restrict__ gate) {
    __shared__ float t[32][33];
    int b = blockIdx.x;
    int tid = threadIdx.x;
    if (b < SF_BLOCKS) {
        // ---- feat -> bf16 (pad rows zeroed) ----
        int i = b * 256 + tid;
        size_t base = (size_t)i * 8;
        if (i >= N_NODES * IN_DIM / 8) {
            *(uint4*)(Fhi + base) = make_uint4(0, 0, 0, 0);
            return;
        }
        float4 x0 = *(const float4*)(feat + base);
        float4 x1 = *(const float4*)(feat + base + 4);
        float xs[8] = {x0.x, x0.y, x0.z, x0.w, x1.x, x1.y, x1.z, x1.w};
        union { u16 s[8]; uint4 v; } h;
#pragma unroll
        for (int j = 0; j < 8; j++) h.s[j] = bf_hi(xs[j]);
        *(uint4*)(Fhi + base) = h.v;
    } else if (b < SF_BLOCKS + SW_BLOCKS) {
        // ---- transpose + split weights: W[k][n] -> Wt[n][k] hi/lo ----
        int bb = b - SF_BLOCKS;
        int kx = bb & 15, ny = (bb >> 4) & 15, w = bb >> 8;
        int ncols = (w == 3) ? 256 : 512;
        int n0 = ny * 32;
        if (n0 >= ncols) return;
        const float* W = (w == 0) ? Ws : ((w == 1) ? Wd : ((w == 2) ? Wk : Wr));
        size_t obase = (size_t)w * 512 * 512;
        int k0 = kx * 32;
        int tx = tid & 31, ty = tid >> 5;  // 32 x 8
#pragma unroll
        for (int i = 0; i < 4; i++)
            t[ty * 4 + i][tx] = W[(size_t)(k0 + ty * 4 + i) * ncols + n0 + tx];
        __syncthreads();
#pragma unroll
        for (int i = 0; i < 4; i++) {
            float x = t[tx][ty * 4 + i];  // = W[k0+tx][n0+ty*4+i]
            u16 hh = bf_hi(x);
            size_t o = obase + (size_t)(n0 + ty * 4 + i) * 512 + k0 + tx;
            Whi[o] = hh;
            Wlo[o] = bf_hi(x - bf_val(hh));
        }
    } else if (b < SF_BLOCKS + SW_BLOCKS + INIT_BLOCKS) {
        // ---- init: zero counters/accumulators (counts zeroed by memset) --
        int i = (b - SF_BLOCKS - SW_BLOCKS) * 256 + tid;
        if (i < N_NODES) { cursor[i] = 0; gate[i] = 0.f; }
        if (i < 1024) stats[i] = 0.f;
        if (i < N_GRAPH * HID) h_gnum[i] = 0.f;
        if (i < N_GRAPH) gden[i] = 0.f;
    } else {
        // ---- in-degree histogram (dst is a kernel input) ----
        int e = (b - SF_BLOCKS - SW_BLOCKS - INIT_BLOCKS) * 256 + tid;
        if (e < N_EDGES) atomicAdd(&counts[dst[e]], 1);
    }
}

// ------- fused triple MFMA GEMM, TRANSPOSED-C epilogue ------------------
// m97-style staging: BOTH A and B via global_load_lds width-16 into linear
// XOR-swizzled LDS double buffers (inverse-swizzled global source, same
// XOR on ds_read offsets).  FS/FD outputs are stored as f16 (edge phase
// uses packed-f16 math); h1 skip stays bf16 hi/lo for BN precision.
// scan_local rides along as blocks >= TRIPLE_BLOCKS (counts complete:
// histogram runs in prep, which precedes this kernel on the stream).
__global__ __launch_bounds__(256) void gemm_mfma_triple(
    const u16* __restrict__ Fhi, const u16* __restrict__ Wthi,
    const float* __restrict__ b_src, const float* __restrict__ b_dst,
    const float* __restrict__ b_skip,
    u16* __restrict__ FS16, u16* __restrict__ FD16,
    u16* __restrict__ h1hi, u16* __restrict__ h1lo,
    const int* __restrict__ counts, int* __restrict__ row_ptr,
    int* __restrict__ bsum) {
    __shared__ u16 S[2][2][8192];  // [buf][A/B][128 rows x 64 k] = 64 KB
    int b = blockIdx.x;
    int tid = threadIdx.x;
    if (b >= TRIPLE_BLOCKS) {  // scan_local rider
        int* buf = (int*)&S[0][0][0];
        int bb = b - TRIPLE_BLOCKS;
        int i = bb * 256 + tid;
        buf[tid] = (i < N_NODES) ? counts[i] : 0;
        __syncthreads();
        for (int off = 1; off < 256; off <<= 1) {
            int t = (tid >= off) ? buf[tid - off] : 0;
            __syncthreads();
            buf[tid] += t;
            __syncthreads();
        }
        if (i < N_NODES) row_ptr[i + 1] = buf[tid];
        if (tid == 255) bsum[bb] = buf[255];
        return;
    }
    int xcd = b & 7, slot = b >> 3;
    int rt = (slot / 12) * 8 + xcd;
    if (rt >= N_RT) return;
    int cw = slot % 12;
    int w_idx = cw >> 2;
    int col0 = (cw & 3) * 128;
    int row0 = rt * 128;
    int lane = tid & 63, wave = tid >> 6;
    int wm = (wave & 1) * 64, wn = (wave >> 1) * 64;
    int quad = lane >> 4, l16 = lane & 15;

    // staging geometry: instr i = wave*4+j covers tile rows [i*8, i*8+8);
    // lane l -> row i*8 + (l>>3), source k offset = 8*((l&7)^(l>>3))
    int lrow = lane >> 3;                   // 0..7
    int kswz = ((lane & 7) ^ lrow) << 3;    // u16 units
    const u16* aS = Fhi + (size_t)(row0 + wave * 32 + lrow) * 512 + kswz;
    const u16* bS = Wthi + (size_t)w_idx * 512 * 512 +
                    (size_t)(col0 + wave * 32 + lrow) * 512 + kswz;

#define STAGE(buf, kk)                                                        \
    do {                                                                      \
        gload16(aS + (size_t)(kk) * 64,         &S[buf][0][(wave * 4 + 0) * 512]); \
        gload16(bS + (size_t)(kk) * 64,         &S[buf][1][(wave * 4 + 0) * 512]); \
        gload16(aS + 4096 + (size_t)(kk) * 64,  &S[buf][0][(wave * 4 + 1) * 512]); \
        gload16(bS + 4096 + (size_t)(kk) * 64,  &S[buf][1][(wave * 4 + 1) * 512]); \
        gload16(aS + 8192 + (size_t)(kk) * 64,  &S[buf][0][(wave * 4 + 2) * 512]); \
        gload16(bS + 8192 + (size_t)(kk) * 64,  &S[buf][1][(wave * 4 + 2) * 512]); \
        gload16(aS + 12288 + (size_t)(kk) * 64, &S[buf][0][(wave * 4 + 3) * 512]); \
        gload16(bS + 12288 + (size_t)(kk) * 64, &S[buf][1][(wave * 4 + 3) * 512]); \
    } while (0)

    int kx8 = (l16 & 7) << 3;
    int oS0 = (quad * 8) ^ kx8;      // s=0 chunk; s=1 chunk = oS0 ^ 32
    int offA = (wm + l16) * 64;
    int offB = (wn + l16) * 64;

    floatx4 acc[4][4];
#pragma unroll
    for (int i = 0; i < 4; i++)
#pragma unroll
        for (int j = 0; j < 4; j++) acc[i][j] = (floatx4){0.f, 0.f, 0.f, 0.f};

    STAGE(0, 0);
    __syncthreads();  // vmcnt(0) drain: tile 0 resident

#pragma unroll
    for (int kk = 0; kk < 8; kk++) {
        if (kk < 7) STAGE((kk + 1) & 1, kk + 1);  // prefetch next tile
        const u16* A = &S[kk & 1][0][0];
        const u16* B = &S[kk & 1][1][0];
        bf16x8 bv[4][2];
#pragma unroll
        for (int nt = 0; nt < 4; nt++) {
            bv[nt][0] = *(const bf16x8*)&B[offB + nt * 1024 + oS0];
            bv[nt][1] = *(const bf16x8*)&B[offB + nt * 1024 + (oS0 ^ 32)];
        }
#pragma unroll
        for (int mt = 0; mt < 4; mt++) {
            bf16x8 a0 = *(const bf16x8*)&A[offA + mt * 1024 + oS0];
            bf16x8 a1 = *(const bf16x8*)&A[offA + mt * 1024 + (oS0 ^ 32)];
#pragma unroll
            for (int nt = 0; nt < 4; nt++) {
                acc[mt][nt] = __builtin_amdgcn_mfma_f32_16x16x32_bf16(
                    bv[nt][0], a0, acc[mt][nt], 0, 0, 0);  // SWAPPED operands
                acc[mt][nt] = __builtin_amdgcn_mfma_f32_16x16x32_bf16(
                    bv[nt][1], a1, acc[mt][nt], 0, 0, 0);
            }
        }
        __syncthreads();  // drains this wave's prefetch + frees read buffer
    }
#undef STAGE

    // transposed-C epilogue: lane l16 = row m, reg r = col nb+r (consecutive)
    const float* bias = (w_idx == 0) ? b_src : ((w_idx == 1) ? b_dst : b_skip);
    float4 b4[4];
#pragma unroll
    for (int wt = 0; wt < 4; wt++)
        b4[wt] = *(const float4*)(bias + col0 + wn + wt * 16 + quad * 4);
#pragma unroll
    for (int ft = 0; ft < 4; ft++) {
        int m = row0 + wm + ft * 16 + l16;
        if (m >= N_NODES) continue;
        size_t rb = (size_t)m * 512;
#pragma unroll
        for (int wt = 0; wt < 4; wt++) {
            int nb = col0 + wn + wt * 16 + quad * 4;
            float v0 = acc[ft][wt][0] + b4[wt].x;
            float v1 = acc[ft][wt][1] + b4[wt].y;
            float v2 = acc[ft][wt][2] + b4[wt].z;
            float v3 = acc[ft][wt][3] + b4[wt].w;
            if (w_idx <= 1) {
                // FS/FD in f16 (packed-f16 edge math; better mantissa too)
                f16x2 p0; p0[0] = (f16)v0; p0[1] = (f16)v1;
                f16x2 p1; p1[0] = (f16)v2; p1[1] = (f16)v3;
                uint2 wv;
                wv.x = u32_from_h2(p0);
                wv.y = u32_from_h2(p1);
                if (w_idx == 0) *(uint2*)(FS16 + rb + nb) = wv;
                else            *(uint2*)(FD16 + rb + nb) = wv;
            } else {
                u16 h0 = bf_hi(v0), h1_ = bf_hi(v1), h2 = bf_hi(v2), h3 = bf_hi(v3);
                uint2 wv;
                wv.x = (unsigned)h0 | ((unsigned)h1_ << 16);
                wv.y = (unsigned)h2 | ((unsigned)h3 << 16);
                *(uint2*)(h1hi + rb + nb) = wv;
                uint2 lv;
                lv.x = (unsigned)bf_hi(v0 - bf_val(h0)) | ((unsigned)bf_hi(v1 - bf_val(h1_)) << 16);
                lv.y = (unsigned)bf_hi(v2 - bf_val(h2)) | ((unsigned)bf_hi(v3 - bf_val(h3)) << 16);
                *(uint2*)(h1lo + rb + nb) = lv;
            }
        }
    }
}

// ---------------- CSR scan fixup + scatter ----------------
__global__ __launch_bounds__(256) void scan_fixup_kernel(
    const int* __restrict__ bsum, int* __restrict__ row_ptr) {
    __shared__ int red[256];
    int b = blockIdx.x, tid = threadIdx.x;
    red[tid] = (tid < b) ? bsum[tid] : 0;
    __syncthreads();
    for (int off = 128; off > 0; off >>= 1) {
        if (tid < off) red[tid] += red[tid + off];
        __syncthreads();
    }
    int offset = red[0];
    int i = b * 256 + tid;
    if (i < N_NODES) row_ptr[i + 1] += offset;
    if (b == 0 && tid == 0) row_ptr[0] = 0;
}

__global__ void scatter_kernel(const int* __restrict__ src, const int* __restrict__ dst,
                               const int* __restrict__ row_ptr,
                               int* __restrict__ cursor, int* __restrict__ csr_src) {
    int e = blockIdx.x * blockDim.x + threadIdx.x;
    if (e < N_EDGES) {
        int d = dst[e];
        int pos = atomicAdd(&cursor[d], 1);
        csr_src[row_ptr[d] + pos] = src[e];
    }
}

// -------- fused edge phase: ONE WAVE PER NODE (4 nodes/block) -----------
// No LDS, no barriers, no cross-wave reduce: per-head softmax reduce stays
// within 32-lane halves (lanes 0-31 = head 0 ch 0-255, lanes 32-63 = head
// 1).  den is identical across lanes of a half after the shfl reduce, so
// it accumulates per-lane in a register.  Edges processed 2 at a time so
// two independent gather->dot->shfl chains hide L2/L3 latency.
__global__ __launch_bounds__(256) void edge_fused_kernel(
    const u16* __restrict__ FS16, const u16* __restrict__ FD16,
    const float* __restrict__ attn, const int* __restrict__ csr_src,
    const int* __restrict__ row_ptr,
    u16* __restrict__ h1hi, u16* __restrict__ h1lo) {
    int tid = threadIdx.x;
    int lane = tid & 63, wave = tid >> 6;
    int n = blockIdx.x * 4 + wave;
    int beg = row_ptr[n], end = row_ptr[n + 1];

    f16x2 fd2[4], aw2[4];
    {
        uint4 q = *(const uint4*)(FD16 + (size_t)n * 512 + 8 * lane);
        fd2[0] = h2_from_u32(q.x); fd2[1] = h2_from_u32(q.y);
        fd2[2] = h2_from_u32(q.z); fd2[3] = h2_from_u32(q.w);
        float4 a0 = *(const float4*)(attn + 8 * lane);
        float4 a1 = *(const float4*)(attn + 8 * lane + 4);
        aw2[0][0] = (f16)a0.x; aw2[0][1] = (f16)a0.y;
        aw2[1][0] = (f16)a0.z; aw2[1][1] = (f16)a0.w;
        aw2[2][0] = (f16)a1.x; aw2[2][1] = (f16)a1.y;
        aw2[3][0] = (f16)a1.z; aw2[3][1] = (f16)a1.w;
    }

    const f16x2 sl2 = {(f16)SLOPE, (f16)SLOPE};
    float acc[8] = {0.f, 0.f, 0.f, 0.f, 0.f, 0.f, 0.f, 0.f};
    float den = 0.f;
    const u16* FSb = FS16 + 8 * lane;

    int j = beg;
    for (; j + 1 < end; j += 2) {
        int s0 = csr_src[j];
        int s1 = csr_src[j + 1];
        uint4 q0 = *(const uint4*)(FSb + (size_t)s0 * 512);
        uint4 q1 = *(const uint4*)(FSb + (size_t)s1 * 512);
        f16x2 f0[4], f1[4];
        f0[0] = h2_from_u32(q0.x); f0[1] = h2_from_u32(q0.y);
        f0[2] = h2_from_u32(q0.z); f0[3] = h2_from_u32(q0.w);
        f1[0] = h2_from_u32(q1.x); f1[1] = h2_from_u32(q1.y);
        f1[2] = h2_from_u32(q1.z); f1[3] = h2_from_u32(q1.w);
        float p0 = 0.f, p1 = 0.f;
#pragma unroll
        for (int k = 0; k < 4; k++) {
            f16x2 sm0 = f0[k] + fd2[k];
            f16x2 m0 = __builtin_elementwise_max(sm0, sm0 * sl2);
            p0 = __builtin_amdgcn_fdot2(m0, aw2[k], p0, false);
            f16x2 sm1 = f1[k] + fd2[k];
            f16x2 m1 = __builtin_elementwise_max(sm1, sm1 * sl2);
            p1 = __builtin_amdgcn_fdot2(m1, aw2[k], p1, false);
        }
#pragma unroll
        for (int off = 16; off > 0; off >>= 1) {
            p0 += __shfl_xor(p0, off, 64);
            p1 += __shfl_xor(p1, off, 64);
        }
        float e0 = __expf(p0);  // shift-invariant: no max pass needed
        float e1 = __expf(p1);
#pragma unroll
        for (int k = 0; k < 4; k++) {
            acc[2 * k]     += e0 * (float)f0[k][0] + e1 * (float)f1[k][0];
            acc[2 * k + 1] += e0 * (float)f0[k][1] + e1 * (float)f1[k][1];
        }
        den += e0 + e1;
    }
    if (j < end) {  // odd-degree tail
        int s = csr_src[j];
        uint4 q = *(const uint4*)(FSb + (size_t)s * 512);
        f16x2 f2[4];
        f2[0] = h2_from_u32(q.x); f2[1] = h2_from_u32(q.y);
        f2[2] = h2_from_u32(q.z); f2[3] = h2_from_u32(q.w);
        float p = 0.f;
#pragma unroll
        for (int k = 0; k < 4; k++) {
            f16x2 sm = f2[k] + fd2[k];
            f16x2 m = __builtin_elementwise_max(sm, sm * sl2);
            p = __builtin_amdgcn_fdot2(m, aw2[k], p, false);
        }
#pragma unroll
        for (int off = 16; off > 0; off >>= 1) p += __shfl_xor(p, off, 64);
        float ex = __expf(p);
#pragma unroll
        for (int k = 0; k < 4; k++) {
            acc[2 * k]     += ex * (float)f2[k][0];
            acc[2 * k + 1] += ex * (float)f2[k][1];
        }
        den += ex;
    }

    float inv = den > 0.f ? 1.f / den : 0.f;
    size_t base = (size_t)n * 512 + 8 * lane;
    union { u16 s[8]; uint4 v; } qh, ql;
    qh.v = *(const uint4*)(h1hi + base);
    ql.v = *(const uint4*)(h1lo + base);
#pragma unroll
    for (int k = 0; k < 8; k++) {
        float skip = bf_val(qh.s[k]) + bf_val(ql.s[k]);
        float x = acc[k] * inv;
        x = x > 0.f ? x : expm1f(x);
        float y = x + skip;
        u16 hh = bf_hi(y);
        qh.s[k] = hh;
        ql.s[k] = bf_hi(y - bf_val(hh));
    }
    *(uint4*)(h1hi + base) = qh.v;
    *(uint4*)(h1lo + base) = ql.v;
}

// ---------------- BatchNorm stats (reads h1hi only: 20.5 MB) ------------
__global__ __launch_bounds__(256) void bn_stats_kernel(const u16* __restrict__ h1hi,
                                                       float* __restrict__ stats,
                                                       int rows_per_block) {
    int tid = threadIdx.x;
    int r0 = blockIdx.x * rows_per_block;
    int r1 = min(r0 + rows_per_block, N_NODES);
    float s0 = 0.f, q0 = 0.f, s1 = 0.f, q1 = 0.f;
    for (int r = r0; r < r1; r++) {
        float a = bf_val(h1hi[(size_t)r * F2 + tid]);
        float b = bf_val(h1hi[(size_t)r * F2 + 256 + tid]);
        s0 += a; q0 += a * a;
        s1 += b; q1 += b * b;
    }
    atomicAdd(&stats[tid], s0);
    atomicAdd(&stats[256 + tid], s1);
    atomicAdd(&stats[512 + tid], q0);
    atomicAdd(&stats[512 + 256 + tid], q1);
}

// ---- BN finalize + fold into reducer weights, one kernel ---------------
__global__ __launch_bounds__(256) void bn_fold_kernel(
    const float* __restrict__ stats, const float* __restrict__ gamma,
    const float* __restrict__ beta,
    const u16* __restrict__ Whi3, const u16* __restrict__ Wlo3,
    const float* __restrict__ b_red,
    u16* __restrict__ Wphi, u16* __restrict__ Wplo, float* __restrict__ bias2) {
    __shared__ float sScale[512], sShift[512];
    __shared__ float red[256];
    int n = blockIdx.x, tid = threadIdx.x;
    for (int c = tid; c < 512; c += 256) {
        float mu = stats[c] / (float)N_NODES;
        float var = stats[512 + c] / (float)N_NODES - mu * mu;
        float sc = gamma[c] * rsqrtf(var + EPS_BN);
        sScale[c] = sc;
        sShift[c] = beta[c] - mu * sc;
    }
    __syncthreads();
    float part = 0.f;
    for (int k = tid; k < 512; k += 256) {
        size_t o = (size_t)n * 512 + k;
        float w = bf_val(Whi3[o]) + bf_val(Wlo3[o]);
        part += sShift[k] * w;
        float wp = w * sScale[k];
        u16 hh = bf_hi(wp);
        Wphi[o] = hh;
        Wplo[o] = bf_hi(wp - bf_val(hh));
    }
    red[tid] = part; __syncthreads();
    for (int off = 128; off > 0; off >>= 1) {
        if (tid < off) red[tid] += red[tid + off];
        __syncthreads();
    }
    if (tid == 0) bias2[n] = b_red[n] + red[0];
}

// ------- reducer GEMM: lean 3-term, TRANSPOSED-C (float4 stores) --------
__global__ __launch_bounds__(256) void gemm_mfma_red(
    const u16* __restrict__ Ahi, const u16* __restrict__ Alo,
    const u16* __restrict__ Bhi, const u16* __restrict__ Blo,
    const float* __restrict__ bias2, const float* __restrict__ wg,
    float* __restrict__ hr, float* __restrict__ gate) {
    __shared__ u16 AsHi[128 * 40];
    __shared__ u16 AsLo[128 * 40];
    int tid = threadIdx.x;
    int row0 = blockIdx.x * 128;
    int col0 = blockIdx.y * 128;
    int lane = tid & 63, wave = tid >> 6;
    int wm = (wave & 1) * 64, wn = (wave >> 1) * 64;
    int quad = lane >> 4, l16 = lane & 15;

    int sr = tid >> 1, sh = (tid & 1) * 16;
    int grow = row0 + sr;
    bool ok = grow < N_NODES;
    u16* sH = &AsHi[sr * 40 + sh];
    u16* sL = &AsLo[sr * 40 + sh];

    const u16* bPh[4];
    const u16* bPl[4];
#pragma unroll
    for (int nt = 0; nt < 4; nt++) {
        size_t o = (size_t)(col0 + wn + nt * 16 + l16) * 512 + quad * 8;
        bPh[nt] = Bhi + o;
        bPl[nt] = Blo + o;
    }

    floatx4 acc[4][4];
#pragma unroll
    for (int i = 0; i < 4; i++)
#pragma unroll
        for (int j = 0; j < 4; j++) acc[i][j] = (floatx4){0.f, 0.f, 0.f, 0.f};

    for (int k0 = 0; k0 < 512; k0 += 32) {
        uint4 h0 = make_uint4(0, 0, 0, 0), h1v = h0, l0 = h0, l1 = h0;
        if (ok) {
            const u16* g = Ahi + (size_t)grow * 512 + k0 + sh;
            const u16* gl = Alo + (size_t)grow * 512 + k0 + sh;
            h0 = *(const uint4*)(g);
            h1v = *(const uint4*)(g + 8);
            l0 = *(const uint4*)(gl);
            l1 = *(const uint4*)(gl + 8);
        }
        union { uint4 u; bf16x8 v; } bh[4], bl[4];
#pragma unroll
        for (int nt = 0; nt < 4; nt++) {
            bh[nt].u = *(const uint4*)(bPh[nt] + k0);
            bl[nt].u = *(const uint4*)(bPl[nt] + k0);
        }
        __syncthreads();
        *(uint4*)(sH + 0) = h0;
        *(uint4*)(sH + 8) = h1v;
        *(uint4*)(sL + 0) = l0;
        *(uint4*)(sL + 8) = l1;
        __syncthreads();
#pragma unroll
        for (int mt = 0; mt < 4; mt++) {
            int me = (wm + mt * 16 + l16) * 40 + quad * 8;
            bf16x8 ah = *(const bf16x8*)&AsHi[me];
            bf16x8 al = *(const bf16x8*)&AsLo[me];
#pragma unroll
            for (int nt = 0; nt < 4; nt++) {
                acc[mt][nt] = __builtin_amdgcn_mfma_f32_16x16x32_bf16(bh[nt].v, ah, acc[mt][nt], 0, 0, 0);
                acc[mt][nt] = __builtin_amdgcn_mfma_f32_16x16x32_bf16(bl[nt].v, ah, acc[mt][nt], 0, 0, 0);
                acc[mt][nt] = __builtin_amdgcn_mfma_f32_16x16x32_bf16(bh[nt].v, al, acc[mt][nt], 0, 0, 0);
            }
        }
    }

    // transposed-C epilogue: lane l16 = row m; reg r = col (consecutive)
    float4 b4[4], w4[4];
#pragma unroll
    for (int wt = 0; wt < 4; wt++) {
        int nb = col0 + wn + wt * 16 + quad * 4;
        b4[wt] = *(const float4*)(bias2 + nb);
        w4[wt] = *(const float4*)(wg + nb);
    }
#pragma unroll
    for (int ft = 0; ft < 4; ft++) {
        int m = row0 + wm + ft * 16 + l16;
        bool ok2 = m < N_NODES;
        float g = 0.f;
#pragma unroll
        for (int wt = 0; wt < 4; wt++) {
            float4 v;
            v.x = acc[ft][wt][0] + b4[wt].x;
            v.y = acc[ft][wt][1] + b4[wt].y;
            v.z = acc[ft][wt][2] + b4[wt].z;
            v.w = acc[ft][wt][3] + b4[wt].w;
            g += v.x * w4[wt].x + v.y * w4[wt].y + v.z * w4[wt].z + v.w * w4[wt].w;
            if (ok2) *(float4*)(hr + (size_t)m * HID + col0 + wn + wt * 16 + quad * 4) = v;
        }
        g += __shfl_xor(g, 16, 64);
        g += __shfl_xor(g, 32, 64);
        if (ok2 && lane < 16) atomicAdd(&gate[m], g);
    }
}

// ---------------- per-graph attention pooling: 8 partial blocks / graph -
__device__ __forceinline__ int lower_bound_dev(const int* a, int n, int v) {
    int lo = 0, hi = n;
    while (lo < hi) {
        int mid = (lo + hi) >> 1;
        if (a[mid] < v) lo = mid + 1; else hi = mid;
    }
    return lo;
}

__global__ __launch_bounds__(256) void pool_partial_kernel(
    const float* __restrict__ hr, const float* __restrict__ gate,
    const int* __restrict__ gids, float* __restrict__ h_gnum,
    float* __restrict__ gden) {
    int b = blockIdx.x;
    int g = b >> 3, part = b & 7;
    int tid = threadIdx.x;
    int start = lower_bound_dev(gids, N_NODES, g);
    int end = lower_bound_dev(gids, N_NODES, g + 1);
    int span = end - start;
    int p_beg = start + (span * part) / 8;
    int p_end = start + (span * (part + 1)) / 8;
    if (p_beg >= p_end) return;
    __shared__ float wa[256];
    __shared__ float red[256];
    float acc = 0.f, denacc = 0.f;
    for (int cbeg = p_beg; cbeg < p_end; cbeg += 256) {
        int c = min(256, p_end - cbeg);
        float e = 0.f;
        if (tid < c) { e = expf(gate[cbeg + tid]); wa[tid] = e; }  // |gate| << 1: safe
        red[tid] = (tid < c) ? e : 0.f;
        __syncthreads();
        for (int off = 128; off > 0; off >>= 1) {
            if (tid < off) red[tid] += red[tid + off];
            __syncthreads();
        }
        denacc += red[0];
        for (int i = 0; i < c; i++) acc += wa[i] * hr[(size_t)(cbeg + i) * HID + tid];
        __syncthreads();
    }
    atomicAdd(&h_gnum[g * HID + tid], acc);
    if (tid == 0) atomicAdd(&gden[g], denacc);
}

// ---------------- classifier (finalizes pooling divide) -----------------
__global__ __launch_bounds__(128) void classifier_kernel(
    const float* __restrict__ h_gnum, const float* __restrict__ gden,
    const float* __restrict__ W1, const float* __restrict__ b1,
    const float* __restrict__ W2, const float* __restrict__ b2,
    float* __restrict__ out) {
    int g = blockIdx.x;
    int tid = threadIdx.x;  // 128
    __shared__ float hg[256];
    __shared__ float z1[128];
    float d = gden[g];
    float invd = d > 0.f ? 1.f / d : 0.f;
    hg[tid] = h_gnum[g * HID + tid] * invd;
    hg[tid + 128] = h_gnum[g * HID + tid + 128] * invd;
    __syncthreads();
    float a = b1[tid];
#pragma unroll 8
    for (int k = 0; k < 256; k++) a += hg[k] * W1[k * 128 + tid];
    z1[tid] = a > 0.f ? a : 0.f;
    __syncthreads();
    if (tid < 10) {
        float o = b2[tid];
#pragma unroll 8
        for (int j = 0; j < 128; j++) o += z1[j] * W2[j * 10 + tid];
        out[g * 10 + tid] = o;
    }
}

// ---------------- launcher ----------------
extern "C" void kernel_launch(void* const* d_in, const int* in_sizes, int n_in,
                              void* d_out, int out_size, void* d_ws, size_t ws_size,
                              hipStream_t stream) {
    const float* feat   = (const float*)d_in[0];
    const int*   src    = (const int*)d_in[1];
    const int*   dst    = (const int*)d_in[2];
    const int*   gids   = (const int*)d_in[3];
    const float* W_src  = (const float*)d_in[4];
    const float* b_src  = (const float*)d_in[5];
    const float* W_dst  = (const float*)d_in[6];
    const float* b_dst  = (const float*)d_in[7];
    const float* attn   = (const float*)d_in[8];
    const float* W_skip = (const float*)d_in[9];
    const float* b_skip = (const float*)d_in[10];
    const float* gamma  = (const float*)d_in[11];
    const float* beta   = (const float*)d_in[12];
    const float* W_red  = (const float*)d_in[13];
    const float* b_red  = (const float*)d_in[14];
    const float* w_gate = (const float*)d_in[15];
    const float* W1     = (const float*)d_in[17];
    const float* b1     = (const float*)d_in[18];
    const float* W2     = (const float*)d_in[19];
    const float* b2     = (const float*)d_in[20];
    float* out = (float*)d_out;

    char* p = (char*)d_ws;
    auto alloc = [&](size_t bytes) -> char* {
        char* r = p;
        p += (bytes + 255) & ~(size_t)255;
        return r;
    };
    u16*   FS16     = (u16*)alloc((size_t)N_NODES * F2 * 2);
    u16*   FD16     = (u16*)alloc((size_t)N_NODES * F2 * 2);
    u16*   h1hi     = (u16*)alloc((size_t)N_NODES * F2 * 2);
    u16*   h1lo     = (u16*)alloc((size_t)N_NODES * F2 * 2);
    float* gate     = (float*)alloc((size_t)N_NODES * 4);
    float* stats    = (float*)alloc(1024 * 4);
    float* bias2    = (float*)alloc(256 * 4);
    float* h_gnum   = (float*)alloc((size_t)N_GRAPH * HID * 4);
    float* gden     = (float*)alloc((size_t)N_GRAPH * 4);
    int* counts     = (int*)alloc((size_t)N_NODES * 4);
    int* row_ptr    = (int*)alloc((size_t)(N_NODES + 1) * 4);
    int* cursor     = (int*)alloc((size_t)N_NODES * 4);
    int* csr_src    = (int*)alloc((size_t)N_EDGES * 4);
    int* bsum       = (int*)alloc((size_t)SCAN_BLOCKS * 4);
    u16* Fhi        = (u16*)alloc((size_t)RT_PAD * IN_DIM * 2);  // padded; aliased as hr later
    u16* Wthi       = (u16*)alloc((size_t)4 * 512 * 512 * 2);
    u16* Wtlo       = (u16*)alloc((size_t)4 * 512 * 512 * 2);
    u16* Wphi       = (u16*)alloc((size_t)HID * 512 * 2);  // BN-folded reducer weights
    u16* Wplo       = (u16*)alloc((size_t)HID * 512 * 2);
    // hr (20.48 MB) aliases Fhi (20.58 MB): Fhi's last use (input GEMMs)
    // strictly precedes hr's first write (reducer GEMM).
    float* hr = (float*)Fhi;
    (void)ws_size; (void)in_sizes; (void)n_in; (void)out_size;

    const size_t WSZ = (size_t)512 * 512;

    // 0. counts <- 0 (graph-captured memset; hist rides prep)
    hipMemsetAsync(counts, 0, (size_t)N_NODES * 4, stream);

    // 1. prep: feat->bf16 + weight transpose/split + zero-init + dst hist
    prep_kernel<<<PREP_BLOCKS, 256, 0, stream>>>(
        feat, Fhi, W_src, W_dst, W_skip, W_red, Wthi, Wtlo,
        dst, counts, cursor, stats, h_gnum, gden, gate);

    // 2. fused input GEMM triple (gload_lds staging) + scan_local rider
    gemm_mfma_triple<<<TRIPLE_BLOCKS + SCAN_BLOCKS, 256, 0, stream>>>(
        Fhi, Wthi, b_src, b_dst, b_skip, FS16, FD16, h1hi, h1lo,
        counts, row_ptr, bsum);

    // 3-4. CSR fixup + scatter
    scan_fixup_kernel<<<SCAN_BLOCKS, 256, 0, stream>>>(bsum, row_ptr);
    scatter_kernel<<<(N_EDGES + 255) / 256, 256, 0, stream>>>(src, dst, row_ptr, cursor, csr_src);

    // 5. fused edge phase (wave-per-node; packed-f16; ELU+skip RMW)
    edge_fused_kernel<<<N_NODES / 4, 256, 0, stream>>>(
        FS16, FD16, attn, csr_src, row_ptr, h1hi, h1lo);

    // 6-7. BN stats -> finalize+fold into reducer weights (one kernel)
    bn_stats_kernel<<<500, 256, 0, stream>>>(h1hi, stats, 40);
    bn_fold_kernel<<<HID, 256, 0, stream>>>(
        stats, gamma, beta, Wthi + 3 * WSZ, Wtlo + 3 * WSZ, b_red, Wphi, Wplo, bias2);

    // 8. hr = h1 @ W' + bias'  (3-term MFMA; gate fused; float4 stores)
    dim3 g256((N_NODES + 127) / 128, 2);
    gemm_mfma_red<<<g256, 256, 0, stream>>>(
        h1hi, h1lo, Wphi, Wplo, bias2, w_gate, hr, gate);

    // 9. per-graph pooling (8 partial blocks per graph)
    pool_partial_kernel<<<N_GRAPH * 8, 256, 0, stream>>>(hr, gate, gids, h_gnum, gden);

    // 10. classifier (+ pooling divide)
    classifier_kernel<<<N_GRAPH, 128, 0, stream>>>(h_gnum, gden, W1, b1, W2, b2, out);
}

// Round 4
// 357.822 us; speedup vs baseline: 1.0429x; 1.0429x over previous
//
#include <hip/hip_runtime.h>
#include <math.h>

#define N_NODES 20000
#define N_EDGES 320000
#define N_GRAPH 64
#define IN_DIM  512
#define HID     256
#define F2      512   // HEADS*HID
#define EPS_BN  1e-5f
#define SLOPE   0.2f
#define SCAN_BLOCKS 79   // ceil(20000/256)
#define N_RT    157      // ceil(20000/128) row tiles
#define RT_PAD  20096    // 157*128: padded Fhi rows so tail A-loads are in-bounds

// prep mega-kernel block ranges (init + split_feat + split_wt + hist fused)
#define SF_BLOCKS   5024   // RT_PAD*512/8/256
#define SW_BLOCKS   1024   // 16 x 16 x 4
#define INIT_BLOCKS 79
#define HIST_BLOCKS 1250
#define PREP_BLOCKS (SF_BLOCKS + SW_BLOCKS + INIT_BLOCKS + HIST_BLOCKS)
// triple launch: 1920 GEMM blocks + 79 scan_local rider blocks
#define TRIPLE_BLOCKS 1920

typedef unsigned short u16;
typedef __attribute__((ext_vector_type(8))) short bf16x8;
typedef __attribute__((ext_vector_type(4))) float floatx4;
typedef _Float16 f16;
typedef __attribute__((ext_vector_type(2))) f16 f16x2;

// bf16 helpers: storage = upper 16 bits of fp32, round-to-nearest-even
__device__ __forceinline__ u16 bf_hi(float x) {
    unsigned int u = __float_as_uint(x);
    return (u16)((u + 0x7fffu + ((u >> 16) & 1u)) >> 16);
}
__device__ __forceinline__ float bf_val(u16 h) {
    return __uint_as_float((unsigned int)h << 16);
}
__device__ __forceinline__ f16x2 h2_from_u32(unsigned int u) {
    return __builtin_bit_cast(f16x2, u);
}
__device__ __forceinline__ unsigned int u32_from_h2(f16x2 h) {
    return __builtin_bit_cast(unsigned int, h);
}

// async global->LDS DMA, 16B per lane, dest = uniform base + lane*16
__device__ __forceinline__ void gload16(const u16* g, u16* l) {
    __builtin_amdgcn_global_load_lds(
        (const __attribute__((address_space(1))) void*)g,
        (__attribute__((address_space(3))) void*)l, 16, 0, 0);
}

// ------- prep mega-kernel: split_feat + split_wt + init + hist ----------
__global__ __launch_bounds__(256) void prep_kernel(
    const float* __restrict__ feat, u16* __restrict__ Fhi,
    const float* __restrict__ Ws, const float* __restrict__ Wd,
    const float* __restrict__ Wk, const float* __restrict__ Wr,
    u16* __restrict__ Whi, u16* __restrict__ Wlo,
    const int* __restrict__ dst, int* __restrict__ counts,
    int* __restrict__ cursor,
    float* __restrict__ stats, float* __restrict__ h_gnum,
    float* __restrict__ gden, float* __restrict__ gate) {
    __shared__ float t[32][33];
    int b = blockIdx.x;
    int tid = threadIdx.x;
    if (b < SF_BLOCKS) {
        // ---- feat -> bf16 (pad rows zeroed) ----
        int i = b * 256 + tid;
        size_t base = (size_t)i * 8;
        if (i >= N_NODES * IN_DIM / 8) {
            *(uint4*)(Fhi + base) = make_uint4(0, 0, 0, 0);
            return;
        }
        float4 x0 = *(const float4*)(feat + base);
        float4 x1 = *(const float4*)(feat + base + 4);
        float xs[8] = {x0.x, x0.y, x0.z, x0.w, x1.x, x1.y, x1.z, x1.w};
        union { u16 s[8]; uint4 v; } h;
#pragma unroll
        for (int j = 0; j < 8; j++) h.s[j] = bf_hi(xs[j]);
        *(uint4*)(Fhi + base) = h.v;
    } else if (b < SF_BLOCKS + SW_BLOCKS) {
        // ---- transpose + split weights: W[k][n] -> Wt[n][k] hi/lo ----
        int bb = b - SF_BLOCKS;
        int kx = bb & 15, ny = (bb >> 4) & 15, w = bb >> 8;
        int ncols = (w == 3) ? 256 : 512;
        int n0 = ny * 32;
        if (n0 >= ncols) return;
        const float* W = (w == 0) ? Ws : ((w == 1) ? Wd : ((w == 2) ? Wk : Wr));
        size_t obase = (size_t)w * 512 * 512;
        int k0 = kx * 32;
        int tx = tid & 31, ty = tid >> 5;  // 32 x 8
#pragma unroll
        for (int i = 0; i < 4; i++)
            t[ty * 4 + i][tx] = W[(size_t)(k0 + ty * 4 + i) * ncols + n0 + tx];
        __syncthreads();
#pragma unroll
        for (int i = 0; i < 4; i++) {
            float x = t[tx][ty * 4 + i];  // = W[k0+tx][n0+ty*4+i]
            u16 hh = bf_hi(x);
            size_t o = obase + (size_t)(n0 + ty * 4 + i) * 512 + k0 + tx;
            Whi[o] = hh;
            Wlo[o] = bf_hi(x - bf_val(hh));
        }
    } else if (b < SF_BLOCKS + SW_BLOCKS + INIT_BLOCKS) {
        // ---- init: zero counters/accumulators (counts zeroed by memset) --
        int i = (b - SF_BLOCKS - SW_BLOCKS) * 256 + tid;
        if (i < N_NODES) { cursor[i] = 0; gate[i] = 0.f; }
        if (i < 1024) stats[i] = 0.f;
        if (i < N_GRAPH * HID) h_gnum[i] = 0.f;
        if (i < N_GRAPH) gden[i] = 0.f;
    } else {
        // ---- in-degree histogram (dst is a kernel input) ----
        int e = (b - SF_BLOCKS - SW_BLOCKS - INIT_BLOCKS) * 256 + tid;
        if (e < N_EDGES) atomicAdd(&counts[dst[e]], 1);
    }
}

// ------- fused triple MFMA GEMM, LDS-staged coalesced epilogue ----------
// Staging: A and B via global_load_lds width-16 into linear XOR-swizzled
// LDS double buffers.  Epilogue: the transposed-C fragments (lane=row,
// 8B/lane -> 64 cache lines per store instr!) are first staged into the
// now-free 64KB LDS buffer, then stored coalesced (16B/lane, 4 contiguous
// 256B row segments per instr = 8 lines, 8x fewer L2 store transactions).
// scan_local rides along as blocks >= TRIPLE_BLOCKS.
__global__ __launch_bounds__(256) void gemm_mfma_triple(
    const u16* __restrict__ Fhi, const u16* __restrict__ Wthi,
    const float* __restrict__ b_src, const float* __restrict__ b_dst,
    const float* __restrict__ b_skip,
    u16* __restrict__ FS16, u16* __restrict__ FD16,
    u16* __restrict__ h1hi, u16* __restrict__ h1lo,
    const int* __restrict__ counts, int* __restrict__ row_ptr,
    int* __restrict__ bsum) {
    __shared__ u16 S[2][2][8192];  // [buf][A/B][128 rows x 64 k] = 64 KB
    int b = blockIdx.x;
    int tid = threadIdx.x;
    if (b >= TRIPLE_BLOCKS) {  // scan_local rider
        int* buf = (int*)&S[0][0][0];
        int bb = b - TRIPLE_BLOCKS;
        int i = bb * 256 + tid;
        buf[tid] = (i < N_NODES) ? counts[i] : 0;
        __syncthreads();
        for (int off = 1; off < 256; off <<= 1) {
            int t = (tid >= off) ? buf[tid - off] : 0;
            __syncthreads();
            buf[tid] += t;
            __syncthreads();
        }
        if (i < N_NODES) row_ptr[i + 1] = buf[tid];
        if (tid == 255) bsum[bb] = buf[255];
        return;
    }
    int xcd = b & 7, slot = b >> 3;
    int rt = (slot / 12) * 8 + xcd;
    if (rt >= N_RT) return;
    int cw = slot % 12;
    int w_idx = cw >> 2;
    int col0 = (cw & 3) * 128;
    int row0 = rt * 128;
    int lane = tid & 63, wave = tid >> 6;
    int wm = (wave & 1) * 64, wn = (wave >> 1) * 64;
    int quad = lane >> 4, l16 = lane & 15;

    // staging geometry: instr i = wave*4+j covers tile rows [i*8, i*8+8);
    // lane l -> row i*8 + (l>>3), source k offset = 8*((l&7)^(l>>3))
    int lrow = lane >> 3;                   // 0..7
    int kswz = ((lane & 7) ^ lrow) << 3;    // u16 units
    const u16* aS = Fhi + (size_t)(row0 + wave * 32 + lrow) * 512 + kswz;
    const u16* bS = Wthi + (size_t)w_idx * 512 * 512 +
                    (size_t)(col0 + wave * 32 + lrow) * 512 + kswz;

#define STAGE(buf, kk)                                                        \
    do {                                                                      \
        gload16(aS + (size_t)(kk) * 64,         &S[buf][0][(wave * 4 + 0) * 512]); \
        gload16(bS + (size_t)(kk) * 64,         &S[buf][1][(wave * 4 + 0) * 512]); \
        gload16(aS + 4096 + (size_t)(kk) * 64,  &S[buf][0][(wave * 4 + 1) * 512]); \
        gload16(bS + 4096 + (size_t)(kk) * 64,  &S[buf][1][(wave * 4 + 1) * 512]); \
        gload16(aS + 8192 + (size_t)(kk) * 64,  &S[buf][0][(wave * 4 + 2) * 512]); \
        gload16(bS + 8192 + (size_t)(kk) * 64,  &S[buf][1][(wave * 4 + 2) * 512]); \
        gload16(aS + 12288 + (size_t)(kk) * 64, &S[buf][0][(wave * 4 + 3) * 512]); \
        gload16(bS + 12288 + (size_t)(kk) * 64, &S[buf][1][(wave * 4 + 3) * 512]); \
    } while (0)

    int kx8 = (l16 & 7) << 3;
    int oS0 = (quad * 8) ^ kx8;      // s=0 chunk; s=1 chunk = oS0 ^ 32
    int offA = (wm + l16) * 64;
    int offB = (wn + l16) * 64;

    floatx4 acc[4][4];
#pragma unroll
    for (int i = 0; i < 4; i++)
#pragma unroll
        for (int j = 0; j < 4; j++) acc[i][j] = (floatx4){0.f, 0.f, 0.f, 0.f};

    STAGE(0, 0);
    __syncthreads();  // vmcnt(0) drain: tile 0 resident

#pragma unroll
    for (int kk = 0; kk < 8; kk++) {
        if (kk < 7) STAGE((kk + 1) & 1, kk + 1);  // prefetch next tile
        const u16* A = &S[kk & 1][0][0];
        const u16* B = &S[kk & 1][1][0];
        bf16x8 bv[4][2];
#pragma unroll
        for (int nt = 0; nt < 4; nt++) {
            bv[nt][0] = *(const bf16x8*)&B[offB + nt * 1024 + oS0];
            bv[nt][1] = *(const bf16x8*)&B[offB + nt * 1024 + (oS0 ^ 32)];
        }
#pragma unroll
        for (int mt = 0; mt < 4; mt++) {
            bf16x8 a0 = *(const bf16x8*)&A[offA + mt * 1024 + oS0];
            bf16x8 a1 = *(const bf16x8*)&A[offA + mt * 1024 + (oS0 ^ 32)];
#pragma unroll
            for (int nt = 0; nt < 4; nt++) {
                acc[mt][nt] = __builtin_amdgcn_mfma_f32_16x16x32_bf16(
                    bv[nt][0], a0, acc[mt][nt], 0, 0, 0);  // SWAPPED operands
                acc[mt][nt] = __builtin_amdgcn_mfma_f32_16x16x32_bf16(
                    bv[nt][1], a1, acc[mt][nt], 0, 0, 0);
            }
        }
        __syncthreads();  // drains this wave's prefetch + frees read buffer
    }
#undef STAGE

    // ---- epilogue: stage C-tile in LDS, then coalesced 16B stores ------
    // K-loop's final barrier makes S free.  Tile layout: Ctile[128 rows]
    // [16 chunks of 16B], chunk index XOR-swizzled with (row&7) so both
    // the 8B quad writes and the 16B row reads stay <=4-way on banks.
    const float* bias = (w_idx == 0) ? b_src : ((w_idx == 1) ? b_dst : b_skip);
    float4 b4[4];
#pragma unroll
    for (int wt = 0; wt < 4; wt++)
        b4[wt] = *(const float4*)(bias + col0 + wn + wt * 16 + quad * 4);

    u16* C = &S[0][0][0];  // 32768 u16: [0,16384) hi/f16, [16384,32768) lo
#pragma unroll
    for (int ft = 0; ft < 4; ft++) {
        int r = wm + ft * 16 + l16;      // tile-local row
        int rx = r & 7;
#pragma unroll
        for (int wt = 0; wt < 4; wt++) {
            int cb = wn + wt * 16 + quad * 4;            // tile-local col
            int off = r * 128 + (((cb >> 3) ^ rx) << 3) + (cb & 4);
            float v0 = acc[ft][wt][0] + b4[wt].x;
            float v1 = acc[ft][wt][1] + b4[wt].y;
            float v2 = acc[ft][wt][2] + b4[wt].z;
            float v3 = acc[ft][wt][3] + b4[wt].w;
            if (w_idx <= 1) {
                f16x2 p0; p0[0] = (f16)v0; p0[1] = (f16)v1;
                f16x2 p1; p1[0] = (f16)v2; p1[1] = (f16)v3;
                uint2 wv;
                wv.x = u32_from_h2(p0);
                wv.y = u32_from_h2(p1);
                *(uint2*)&C[off] = wv;
            } else {
                u16 h0 = bf_hi(v0), h1_ = bf_hi(v1), h2 = bf_hi(v2), h3 = bf_hi(v3);
                uint2 wv;
                wv.x = (unsigned)h0 | ((unsigned)h1_ << 16);
                wv.y = (unsigned)h2 | ((unsigned)h3 << 16);
                *(uint2*)&C[off] = wv;
                uint2 lv;
                lv.x = (unsigned)bf_hi(v0 - bf_val(h0)) | ((unsigned)bf_hi(v1 - bf_val(h1_)) << 16);
                lv.y = (unsigned)bf_hi(v2 - bf_val(h2)) | ((unsigned)bf_hi(v3 - bf_val(h3)) << 16);
                *(uint2*)&C[16384 + off] = lv;
            }
        }
    }
    __syncthreads();
    // coalesced store: 16 threads/row (16B chunks), 16 rows/instr-group
    {
        int tr = tid >> 4;   // row within group of 16
        int tc = tid & 15;   // 16B chunk
        u16* outp = (w_idx == 0) ? FS16 : ((w_idx == 1) ? FD16 : h1hi);
#pragma unroll
        for (int i = 0; i < 8; i++) {
            int r = i * 16 + tr;
            int m = row0 + r;
            int loff = r * 128 + ((tc ^ (r & 7)) << 3);
            uint4 v = *(const uint4*)&C[loff];
            if (m < N_NODES) {
                *(uint4*)(outp + (size_t)m * 512 + col0 + tc * 8) = v;
                if (w_idx == 2) {
                    uint4 vl = *(const uint4*)&C[16384 + loff];
                    *(uint4*)(h1lo + (size_t)m * 512 + col0 + tc * 8) = vl;
                }
            }
        }
    }
}

// ---------------- CSR scan fixup + scatter ----------------
__global__ __launch_bounds__(256) void scan_fixup_kernel(
    const int* __restrict__ bsum, int* __restrict__ row_ptr) {
    __shared__ int red[256];
    int b = blockIdx.x, tid = threadIdx.x;
    red[tid] = (tid < b) ? bsum[tid] : 0;
    __syncthreads();
    for (int off = 128; off > 0; off >>= 1) {
        if (tid < off) red[tid] += red[tid + off];
        __syncthreads();
    }
    int offset = red[0];
    int i = b * 256 + tid;
    if (i < N_NODES) row_ptr[i + 1] += offset;
    if (b == 0 && tid == 0) row_ptr[0] = 0;
}

__global__ void scatter_kernel(const int* __restrict__ src, const int* __restrict__ dst,
                               const int* __restrict__ row_ptr,
                               int* __restrict__ cursor, int* __restrict__ csr_src) {
    int e = blockIdx.x * blockDim.x + threadIdx.x;
    if (e < N_EDGES) {
        int d = dst[e];
        int pos = atomicAdd(&cursor[d], 1);
        csr_src[row_ptr[d] + pos] = src[e];
    }
}

// -------- fused edge phase: ONE WAVE PER NODE (4 nodes/block) -----------
// No LDS, no barriers, no cross-wave reduce: per-head softmax reduce stays
// within 32-lane halves.  den accumulates per-lane in a register.  Edges
// processed 2 at a time so two independent gather->dot->shfl chains hide
// L2/L3 latency.
__global__ __launch_bounds__(256) void edge_fused_kernel(
    const u16* __restrict__ FS16, const u16* __restrict__ FD16,
    const float* __restrict__ attn, const int* __restrict__ csr_src,
    const int* __restrict__ row_ptr,
    u16* __restrict__ h1hi, u16* __restrict__ h1lo) {
    int tid = threadIdx.x;
    int lane = tid & 63, wave = tid >> 6;
    int n = blockIdx.x * 4 + wave;
    int beg = row_ptr[n], end = row_ptr[n + 1];

    f16x2 fd2[4], aw2[4];
    {
        uint4 q = *(const uint4*)(FD16 + (size_t)n * 512 + 8 * lane);
        fd2[0] = h2_from_u32(q.x); fd2[1] = h2_from_u32(q.y);
        fd2[2] = h2_from_u32(q.z); fd2[3] = h2_from_u32(q.w);
        float4 a0 = *(const float4*)(attn + 8 * lane);
        float4 a1 = *(const float4*)(attn + 8 * lane + 4);
        aw2[0][0] = (f16)a0.x; aw2[0][1] = (f16)a0.y;
        aw2[1][0] = (f16)a0.z; aw2[1][1] = (f16)a0.w;
        aw2[2][0] = (f16)a1.x; aw2[2][1] = (f16)a1.y;
        aw2[3][0] = (f16)a1.z; aw2[3][1] = (f16)a1.w;
    }

    const f16x2 sl2 = {(f16)SLOPE, (f16)SLOPE};
    float acc[8] = {0.f, 0.f, 0.f, 0.f, 0.f, 0.f, 0.f, 0.f};
    float den = 0.f;
    const u16* FSb = FS16 + 8 * lane;

    int j = beg;
    for (; j + 1 < end; j += 2) {
        int s0 = csr_src[j];
        int s1 = csr_src[j + 1];
        uint4 q0 = *(const uint4*)(FSb + (size_t)s0 * 512);
        uint4 q1 = *(const uint4*)(FSb + (size_t)s1 * 512);
        f16x2 f0[4], f1[4];
        f0[0] = h2_from_u32(q0.x); f0[1] = h2_from_u32(q0.y);
        f0[2] = h2_from_u32(q0.z); f0[3] = h2_from_u32(q0.w);
        f1[0] = h2_from_u32(q1.x); f1[1] = h2_from_u32(q1.y);
        f1[2] = h2_from_u32(q1.z); f1[3] = h2_from_u32(q1.w);
        float p0 = 0.f, p1 = 0.f;
#pragma unroll
        for (int k = 0; k < 4; k++) {
            f16x2 sm0 = f0[k] + fd2[k];
            f16x2 m0 = __builtin_elementwise_max(sm0, sm0 * sl2);
            p0 = __builtin_amdgcn_fdot2(m0, aw2[k], p0, false);
            f16x2 sm1 = f1[k] + fd2[k];
            f16x2 m1 = __builtin_elementwise_max(sm1, sm1 * sl2);
            p1 = __builtin_amdgcn_fdot2(m1, aw2[k], p1, false);
        }
#pragma unroll
        for (int off = 16; off > 0; off >>= 1) {
            p0 += __shfl_xor(p0, off, 64);
            p1 += __shfl_xor(p1, off, 64);
        }
        float e0 = __expf(p0);  // shift-invariant: no max pass needed
        float e1 = __expf(p1);
#pragma unroll
        for (int k = 0; k < 4; k++) {
            acc[2 * k]     += e0 * (float)f0[k][0] + e1 * (float)f1[k][0];
            acc[2 * k + 1] += e0 * (float)f0[k][1] + e1 * (float)f1[k][1];
        }
        den += e0 + e1;
    }
    if (j < end) {  // odd-degree tail
        int s = csr_src[j];
        uint4 q = *(const uint4*)(FSb + (size_t)s * 512);
        f16x2 f2[4];
        f2[0] = h2_from_u32(q.x); f2[1] = h2_from_u32(q.y);
        f2[2] = h2_from_u32(q.z); f2[3] = h2_from_u32(q.w);
        float p = 0.f;
#pragma unroll
        for (int k = 0; k < 4; k++) {
            f16x2 sm = f2[k] + fd2[k];
            f16x2 m = __builtin_elementwise_max(sm, sm * sl2);
            p = __builtin_amdgcn_fdot2(m, aw2[k], p, false);
        }
#pragma unroll
        for (int off = 16; off > 0; off >>= 1) p += __shfl_xor(p, off, 64);
        float ex = __expf(p);
#pragma unroll
        for (int k = 0; k < 4; k++) {
            acc[2 * k]     += ex * (float)f2[k][0];
            acc[2 * k + 1] += ex * (float)f2[k][1];
        }
        den += ex;
    }

    float inv = den > 0.f ? 1.f / den : 0.f;
    size_t base = (size_t)n * 512 + 8 * lane;
    union { u16 s[8]; uint4 v; } qh, ql;
    qh.v = *(const uint4*)(h1hi + base);
    ql.v = *(const uint4*)(h1lo + base);
#pragma unroll
    for (int k = 0; k < 8; k++) {
        float skip = bf_val(qh.s[k]) + bf_val(ql.s[k]);
        float x = acc[k] * inv;
        x = x > 0.f ? x : expm1f(x);
        float y = x + skip;
        u16 hh = bf_hi(y);
        qh.s[k] = hh;
        ql.s[k] = bf_hi(y - bf_val(hh));
    }
    *(uint4*)(h1hi + base) = qh.v;
    *(uint4*)(h1lo + base) = ql.v;
}

// ---------------- BatchNorm stats (reads h1hi only: 20.5 MB) ------------
__global__ __launch_bounds__(256) void bn_stats_kernel(const u16* __restrict__ h1hi,
                                                       float* __restrict__ stats,
                                                       int rows_per_block) {
    int tid = threadIdx.x;
    int r0 = blockIdx.x * rows_per_block;
    int r1 = min(r0 + rows_per_block, N_NODES);
    float s0 = 0.f, q0 = 0.f, s1 = 0.f, q1 = 0.f;
    for (int r = r0; r < r1; r++) {
        float a = bf_val(h1hi[(size_t)r * F2 + tid]);
        float b = bf_val(h1hi[(size_t)r * F2 + 256 + tid]);
        s0 += a; q0 += a * a;
        s1 += b; q1 += b * b;
    }
    atomicAdd(&stats[tid], s0);
    atomicAdd(&stats[256 + tid], s1);
    atomicAdd(&stats[512 + tid], q0);
    atomicAdd(&stats[512 + 256 + tid], q1);
}

// ---- BN finalize + fold into reducer weights, one kernel ---------------
__global__ __launch_bounds__(256) void bn_fold_kernel(
    const float* __restrict__ stats, const float* __restrict__ gamma,
    const float* __restrict__ beta,
    const u16* __restrict__ Whi3, const u16* __restrict__ Wlo3,
    const float* __restrict__ b_red,
    u16* __restrict__ Wphi, u16* __restrict__ Wplo, float* __restrict__ bias2) {
    __shared__ float sScale[512], sShift[512];
    __shared__ float red[256];
    int n = blockIdx.x, tid = threadIdx.x;
    for (int c = tid; c < 512; c += 256) {
        float mu = stats[c] / (float)N_NODES;
        float var = stats[512 + c] / (float)N_NODES - mu * mu;
        float sc = gamma[c] * rsqrtf(var + EPS_BN);
        sScale[c] = sc;
        sShift[c] = beta[c] - mu * sc;
    }
    __syncthreads();
    float part = 0.f;
    for (int k = tid; k < 512; k += 256) {
        size_t o = (size_t)n * 512 + k;
        float w = bf_val(Whi3[o]) + bf_val(Wlo3[o]);
        part += sShift[k] * w;
        float wp = w * sScale[k];
        u16 hh = bf_hi(wp);
        Wphi[o] = hh;
        Wplo[o] = bf_hi(wp - bf_val(hh));
    }
    red[tid] = part; __syncthreads();
    for (int off = 128; off > 0; off >>= 1) {
        if (tid < off) red[tid] += red[tid + off];
        __syncthreads();
    }
    if (tid == 0) bias2[n] = b_red[n] + red[0];
}

// ------- reducer GEMM: lean 3-term, TRANSPOSED-C (float4 stores) --------
__global__ __launch_bounds__(256) void gemm_mfma_red(
    const u16* __restrict__ Ahi, const u16* __restrict__ Alo,
    const u16* __restrict__ Bhi, const u16* __restrict__ Blo,
    const float* __restrict__ bias2, const float* __restrict__ wg,
    float* __restrict__ hr, float* __restrict__ gate) {
    __shared__ u16 AsHi[128 * 40];
    __shared__ u16 AsLo[128 * 40];
    int tid = threadIdx.x;
    int row0 = blockIdx.x * 128;
    int col0 = blockIdx.y * 128;
    int lane = tid & 63, wave = tid >> 6;
    int wm = (wave & 1) * 64, wn = (wave >> 1) * 64;
    int quad = lane >> 4, l16 = lane & 15;

    int sr = tid >> 1, sh = (tid & 1) * 16;
    int grow = row0 + sr;
    bool ok = grow < N_NODES;
    u16* sH = &AsHi[sr * 40 + sh];
    u16* sL = &AsLo[sr * 40 + sh];

    const u16* bPh[4];
    const u16* bPl[4];
#pragma unroll
    for (int nt = 0; nt < 4; nt++) {
        size_t o = (size_t)(col0 + wn + nt * 16 + l16) * 512 + quad * 8;
        bPh[nt] = Bhi + o;
        bPl[nt] = Blo + o;
    }

    floatx4 acc[4][4];
#pragma unroll
    for (int i = 0; i < 4; i++)
#pragma unroll
        for (int j = 0; j < 4; j++) acc[i][j] = (floatx4){0.f, 0.f, 0.f, 0.f};

    for (int k0 = 0; k0 < 512; k0 += 32) {
        uint4 h0 = make_uint4(0, 0, 0, 0), h1v = h0, l0 = h0, l1 = h0;
        if (ok) {
            const u16* g = Ahi + (size_t)grow * 512 + k0 + sh;
            const u16* gl = Alo + (size_t)grow * 512 + k0 + sh;
            h0 = *(const uint4*)(g);
            h1v = *(const uint4*)(g + 8);
            l0 = *(const uint4*)(gl);
            l1 = *(const uint4*)(gl + 8);
        }
        union { uint4 u; bf16x8 v; } bh[4], bl[4];
#pragma unroll
        for (int nt = 0; nt < 4; nt++) {
            bh[nt].u = *(const uint4*)(bPh[nt] + k0);
            bl[nt].u = *(const uint4*)(bPl[nt] + k0);
        }
        __syncthreads();
        *(uint4*)(sH + 0) = h0;
        *(uint4*)(sH + 8) = h1v;
        *(uint4*)(sL + 0) = l0;
        *(uint4*)(sL + 8) = l1;
        __syncthreads();
#pragma unroll
        for (int mt = 0; mt < 4; mt++) {
            int me = (wm + mt * 16 + l16) * 40 + quad * 8;
            bf16x8 ah = *(const bf16x8*)&AsHi[me];
            bf16x8 al = *(const bf16x8*)&AsLo[me];
#pragma unroll
            for (int nt = 0; nt < 4; nt++) {
                acc[mt][nt] = __builtin_amdgcn_mfma_f32_16x16x32_bf16(bh[nt].v, ah, acc[mt][nt], 0, 0, 0);
                acc[mt][nt] = __builtin_amdgcn_mfma_f32_16x16x32_bf16(bl[nt].v, ah, acc[mt][nt], 0, 0, 0);
                acc[mt][nt] = __builtin_amdgcn_mfma_f32_16x16x32_bf16(bh[nt].v, al, acc[mt][nt], 0, 0, 0);
            }
        }
    }

    // transposed-C epilogue: lane l16 = row m; reg r = col (consecutive)
    float4 b4[4], w4[4];
#pragma unroll
    for (int wt = 0; wt < 4; wt++) {
        int nb = col0 + wn + wt * 16 + quad * 4;
        b4[wt] = *(const float4*)(bias2 + nb);
        w4[wt] = *(const float4*)(wg + nb);
    }
#pragma unroll
    for (int ft = 0; ft < 4; ft++) {
        int m = row0 + wm + ft * 16 + l16;
        bool ok2 = m < N_NODES;
        float g = 0.f;
#pragma unroll
        for (int wt = 0; wt < 4; wt++) {
            float4 v;
            v.x = acc[ft][wt][0] + b4[wt].x;
            v.y = acc[ft][wt][1] + b4[wt].y;
            v.z = acc[ft][wt][2] + b4[wt].z;
            v.w = acc[ft][wt][3] + b4[wt].w;
            g += v.x * w4[wt].x + v.y * w4[wt].y + v.z * w4[wt].z + v.w * w4[wt].w;
            if (ok2) *(float4*)(hr + (size_t)m * HID + col0 + wn + wt * 16 + quad * 4) = v;
        }
        g += __shfl_xor(g, 16, 64);
        g += __shfl_xor(g, 32, 64);
        if (ok2 && lane < 16) atomicAdd(&gate[m], g);
    }
}

// ---------------- per-graph attention pooling: 8 partial blocks / graph -
__device__ __forceinline__ int lower_bound_dev(const int* a, int n, int v) {
    int lo = 0, hi = n;
    while (lo < hi) {
        int mid = (lo + hi) >> 1;
        if (a[mid] < v) lo = mid + 1; else hi = mid;
    }
    return lo;
}

__global__ __launch_bounds__(256) void pool_partial_kernel(
    const float* __restrict__ hr, const float* __restrict__ gate,
    const int* __restrict__ gids, float* __restrict__ h_gnum,
    float* __restrict__ gden) {
    int b = blockIdx.x;
    int g = b >> 3, part = b & 7;
    int tid = threadIdx.x;
    int start = lower_bound_dev(gids, N_NODES, g);
    int end = lower_bound_dev(gids, N_NODES, g + 1);
    int span = end - start;
    int p_beg = start + (span * part) / 8;
    int p_end = start + (span * (part + 1)) / 8;
    if (p_beg >= p_end) return;
    __shared__ float wa[256];
    __shared__ float red[256];
    float acc = 0.f, denacc = 0.f;
    for (int cbeg = p_beg; cbeg < p_end; cbeg += 256) {
        int c = min(256, p_end - cbeg);
        float e = 0.f;
        if (tid < c) { e = expf(gate[cbeg + tid]); wa[tid] = e; }  // |gate| << 1: safe
        red[tid] = (tid < c) ? e : 0.f;
        __syncthreads();
        for (int off = 128; off > 0; off >>= 1) {
            if (tid < off) red[tid] += red[tid + off];
            __syncthreads();
        }
        denacc += red[0];
        for (int i = 0; i < c; i++) acc += wa[i] * hr[(size_t)(cbeg + i) * HID + tid];
        __syncthreads();
    }
    atomicAdd(&h_gnum[g * HID + tid], acc);
    if (tid == 0) atomicAdd(&gden[g], denacc);
}

// ---------------- classifier (finalizes pooling divide) -----------------
__global__ __launch_bounds__(128) void classifier_kernel(
    const float* __restrict__ h_gnum, const float* __restrict__ gden,
    const float* __restrict__ W1, const float* __restrict__ b1,
    const float* __restrict__ W2, const float* __restrict__ b2,
    float* __restrict__ out) {
    int g = blockIdx.x;
    int tid = threadIdx.x;  // 128
    __shared__ float hg[256];
    __shared__ float z1[128];
    float d = gden[g];
    float invd = d > 0.f ? 1.f / d : 0.f;
    hg[tid] = h_gnum[g * HID + tid] * invd;
    hg[tid + 128] = h_gnum[g * HID + tid + 128] * invd;
    __syncthreads();
    float a = b1[tid];
#pragma unroll 8
    for (int k = 0; k < 256; k++) a += hg[k] * W1[k * 128 + tid];
    z1[tid] = a > 0.f ? a : 0.f;
    __syncthreads();
    if (tid < 10) {
        float o = b2[tid];
#pragma unroll 8
        for (int j = 0; j < 128; j++) o += z1[j] * W2[j * 10 + tid];
        out[g * 10 + tid] = o;
    }
}

// ---------------- launcher ----------------
extern "C" void kernel_launch(void* const* d_in, const int* in_sizes, int n_in,
                              void* d_out, int out_size, void* d_ws, size_t ws_size,
                              hipStream_t stream) {
    const float* feat   = (const float*)d_in[0];
    const int*   src    = (const int*)d_in[1];
    const int*   dst    = (const int*)d_in[2];
    const int*   gids   = (const int*)d_in[3];
    const float* W_src  = (const float*)d_in[4];
    const float* b_src  = (const float*)d_in[5];
    const float* W_dst  = (const float*)d_in[6];
    const float* b_dst  = (const float*)d_in[7];
    const float* attn   = (const float*)d_in[8];
    const float* W_skip = (const float*)d_in[9];
    const float* b_skip = (const float*)d_in[10];
    const float* gamma  = (const float*)d_in[11];
    const float* beta   = (const float*)d_in[12];
    const float* W_red  = (const float*)d_in[13];
    const float* b_red  = (const float*)d_in[14];
    const float* w_gate = (const float*)d_in[15];
    const float* W1     = (const float*)d_in[17];
    const float* b1     = (const float*)d_in[18];
    const float* W2     = (const float*)d_in[19];
    const float* b2     = (const float*)d_in[20];
    float* out = (float*)d_out;

    char* p = (char*)d_ws;
    auto alloc = [&](size_t bytes) -> char* {
        char* r = p;
        p += (bytes + 255) & ~(size_t)255;
        return r;
    };
    u16*   FS16     = (u16*)alloc((size_t)N_NODES * F2 * 2);
    u16*   FD16     = (u16*)alloc((size_t)N_NODES * F2 * 2);
    u16*   h1hi     = (u16*)alloc((size_t)N_NODES * F2 * 2);
    u16*   h1lo     = (u16*)alloc((size_t)N_NODES * F2 * 2);
    float* gate     = (float*)alloc((size_t)N_NODES * 4);
    float* stats    = (float*)alloc(1024 * 4);
    float* bias2    = (float*)alloc(256 * 4);
    float* h_gnum   = (float*)alloc((size_t)N_GRAPH * HID * 4);
    float* gden     = (float*)alloc((size_t)N_GRAPH * 4);
    int* counts     = (int*)alloc((size_t)N_NODES * 4);
    int* row_ptr    = (int*)alloc((size_t)(N_NODES + 1) * 4);
    int* cursor     = (int*)alloc((size_t)N_NODES * 4);
    int* csr_src    = (int*)alloc((size_t)N_EDGES * 4);
    int* bsum       = (int*)alloc((size_t)SCAN_BLOCKS * 4);
    u16* Fhi        = (u16*)alloc((size_t)RT_PAD * IN_DIM * 2);  // padded; aliased as hr later
    u16* Wthi       = (u16*)alloc((size_t)4 * 512 * 512 * 2);
    u16* Wtlo       = (u16*)alloc((size_t)4 * 512 * 512 * 2);
    u16* Wphi       = (u16*)alloc((size_t)HID * 512 * 2);  // BN-folded reducer weights
    u16* Wplo       = (u16*)alloc((size_t)HID * 512 * 2);
    // hr (20.48 MB) aliases Fhi (20.58 MB): Fhi's last use (input GEMMs)
    // strictly precedes hr's first write (reducer GEMM).
    float* hr = (float*)Fhi;
    (void)ws_size; (void)in_sizes; (void)n_in; (void)out_size;

    const size_t WSZ = (size_t)512 * 512;

    // 0. counts <- 0 (graph-captured memset; hist rides prep)
    hipMemsetAsync(counts, 0, (size_t)N_NODES * 4, stream);

    // 1. prep: feat->bf16 + weight transpose/split + zero-init + dst hist
    prep_kernel<<<PREP_BLOCKS, 256, 0, stream>>>(
        feat, Fhi, W_src, W_dst, W_skip, W_red, Wthi, Wtlo,
        dst, counts, cursor, stats, h_gnum, gden, gate);

    // 2. fused input GEMM triple (gload_lds staging; LDS-coalesced stores)
    gemm_mfma_triple<<<TRIPLE_BLOCKS + SCAN_BLOCKS, 256, 0, stream>>>(
        Fhi, Wthi, b_src, b_dst, b_skip, FS16, FD16, h1hi, h1lo,
        counts, row_ptr, bsum);

    // 3-4. CSR fixup + scatter
    scan_fixup_kernel<<<SCAN_BLOCKS, 256, 0, stream>>>(bsum, row_ptr);
    scatter_kernel<<<(N_EDGES + 255) / 256, 256, 0, stream>>>(src, dst, row_ptr, cursor, csr_src);

    // 5. fused edge phase (wave-per-node; packed-f16; ELU+skip RMW)
    edge_fused_kernel<<<N_NODES / 4, 256, 0, stream>>>(
        FS16, FD16, attn, csr_src, row_ptr, h1hi, h1lo);

    // 6-7. BN stats -> finalize+fold into reducer weights (one kernel)
    bn_stats_kernel<<<500, 256, 0, stream>>>(h1hi, stats, 40);
    bn_fold_kernel<<<HID, 256, 0, stream>>>(
        stats, gamma, beta, Wthi + 3 * WSZ, Wtlo + 3 * WSZ, b_red, Wphi, Wplo, bias2);

    // 8. hr = h1 @ W' + bias'  (3-term MFMA; gate fused; float4 stores)
    dim3 g256((N_NODES + 127) / 128, 2);
    gemm_mfma_red<<<g256, 256, 0, stream>>>(
        h1hi, h1lo, Wphi, Wplo, bias2, w_gate, hr, gate);

    // 9. per-graph pooling (8 partial blocks per graph)
    pool_partial_kernel<<<N_GRAPH * 8, 256, 0, stream>>>(hr, gate, gids, h_gnum, gden);

    // 10. classifier (+ pooling divide)
    classifier_kernel<<<N_GRAPH, 128, 0, stream>>>(h_gnum, gden, W1, b1, W2, b2, out);
}